// Round 6
// baseline (178.587 us; speedup 1.0000x reference)
//
#include <hip/hip_runtime.h>

// Problem constants (B=1 fixed)
#define RR     1024
#define NSEQ   128
#define CFEAT  22
#define CMSA   256
#define CPAIR  128
#define NBINS  65

typedef float f4 __attribute__((ext_vector_type(4)));
typedef float f2 __attribute__((ext_vector_type(2)));

// ---------------------------------------------------------------------------
// Kernel 1: per-residue projections + relpos table (128 blocks x 8 rows)
// ---------------------------------------------------------------------------
__global__ __launch_bounds__(256) void k_pre(
    const float* __restrict__ tf,
    const float* __restrict__ Wa, const float* __restrict__ ba,
    const float* __restrict__ Wb, const float* __restrict__ bb,
    const float* __restrict__ Wm2, const float* __restrict__ bm2,
    const float* __restrict__ Wpos, const float* __restrict__ bpos,
    float* __restrict__ a, float* __restrict__ bvp,
    float* __restrict__ tm2, float* __restrict__ pose)
{
    __shared__ float wlds[CFEAT][512];
    __shared__ float rows[8][CFEAT];
    const int t = threadIdx.x;
    const int r0 = blockIdx.x * 8;

    for (int idx = t; idx < 128 * CFEAT; idx += 256) {
        int c = idx / CFEAT, k = idx - c * CFEAT;
        wlds[k][c] = Wa[idx];
    }
    for (int idx = t; idx < 128 * CFEAT; idx += 256) {
        int c = idx / CFEAT, k = idx - c * CFEAT;
        wlds[k][128 + c] = Wb[idx];
    }
    for (int idx = t; idx < 256 * CFEAT; idx += 256) {
        int c = idx / CFEAT, k = idx - c * CFEAT;
        wlds[k][256 + c] = Wm2[idx];
    }
    for (int idx = t; idx < 8 * CFEAT; idx += 256) {
        int rr = idx / CFEAT, k = idx - rr * CFEAT;
        rows[rr][k] = tf[(r0 + rr) * CFEAT + k];
    }
    __syncthreads();

    #pragma unroll
    for (int rr = 0; rr < 8; ++rr) {
        const int r = r0 + rr;
        float s1 = 0.f, s2 = 0.f;
        #pragma unroll
        for (int k = 0; k < CFEAT; ++k) {
            float rv = rows[rr][k];
            s1 += rv * wlds[k][t];        // a (t<128) or bv (t>=128)
            s2 += rv * wlds[k][256 + t];  // tm2
        }
        tm2[r * CMSA + t] = s2 + bm2[t];
        if (t < CPAIR) a[r * CPAIR + t] = s1 + ba[t];
        else           bvp[r * CPAIR + (t - CPAIR)] = s1 + bb[t - CPAIR];
    }

    if (blockIdx.x < NBINS && t < CPAIR)
        pose[blockIdx.x * CPAIR + t] = Wpos[t * NBINS + blockIdx.x] + bpos[t];
}

// ---------------------------------------------------------------------------
// Fused kernel, block-role split (8-block groups, 1:1 ratio).
//   pair role (2048 blocks): 16i x 32j tile of z. a-strip + pose + resi all
//       staged in LDS -> inner loop has ZERO L2 reads -> z uses PLAIN stores
//       (L2 writeback path = fill-calibrated 6.6 TB/s; thrash now harmless).
//   msa role  (2048 blocks): m = msa@Wm1.T + bm1 + tm2, 2 ch/thread weights
//       in registers, NT stores (protects tm2 reads from eviction).
// ---------------------------------------------------------------------------
#define PPB 64  // (n,r) pairs per msa block

__global__ __launch_bounds__(256) void k_fused(
    const int* __restrict__ resi,
    const float* __restrict__ a, const float* __restrict__ bvp,
    const float* __restrict__ pose, float* __restrict__ out_z,
    const float* __restrict__ msa,
    const float* __restrict__ Wm1, const float* __restrict__ bm1,
    const float* __restrict__ tm2, float* __restrict__ out_m)
{
    __shared__ union U {
        struct {                       // pair role: ~49.5 KB
            float aL[32 * CPAIR];      // 16 KB  (32 j-rows of a)
            float poseL[NBINS * CPAIR];// 33.3 KB
            int   rjL[32];
            int   riL[16];
        } p;
        struct { float rows[PPB][24]; } m;  // 6 KB
    } sm;
    const int bx = blockIdx.x;
    const int grp = bx >> 3, sub = bx & 7;
    const int id = (grp >> 1) * 8 + sub;   // role-local block id, 0..2047
    const int t = threadIdx.x;

    if ((grp & 1) == 0) {
        // ---------------- pair role: 16 x 32 tile ----------------
        const int i0 = (id >> 5) * 16;     // 64 i-tiles
        const int j0 = (id & 31) * 32;     // 32 j-tiles

        for (int idx = t; idx < 32 * CPAIR / 4; idx += 256)
            ((f4*)sm.p.aL)[idx] = ((const f4*)(a + (long)j0 * CPAIR))[idx];
        for (int idx = t; idx < NBINS * CPAIR / 4; idx += 256)
            ((f4*)sm.p.poseL)[idx] = ((const f4*)pose)[idx];
        if (t < 32) sm.p.rjL[t] = resi[j0 + t];
        if (t < 16) sm.p.riL[t] = resi[i0 + t];
        __syncthreads();

        const int cb = (t & 31) * 4;  // channel base 0,4,...,124
        const int jo = t >> 5;        // 0..7

        for (int ii = 0; ii < 16; ++ii) {
            const int i = i0 + ii;
            const f4 bvv = *(const f4*)(bvp + (long)i * CPAIR + cb); // L2, 1/ii
            const int ri = sm.p.riL[ii];
            float* dst = out_z + ((long)i * RR + j0) * CPAIR;
            #pragma unroll
            for (int q = 0; q < 4; ++q) {
                const int jl = q * 8 + jo;
                int d = sm.p.rjL[jl] - ri + (NBINS / 2);
                d = min(max(d, 0), NBINS - 1);
                const f4 av = *(const f4*)&sm.p.aL[jl * CPAIR + cb];
                const f4 pv = *(const f4*)&sm.p.poseL[d * CPAIR + cb];
                f4 o = av + bvv + pv;
                *(f4*)(dst + jl * CPAIR + cb) = o;   // PLAIN store -> L2
            }
        }
    } else {
        // ---------------- msa role ----------------
        const long pbase = (long)id * PPB;
        const float* src = msa + pbase * CFEAT;
        for (int idx = t; idx < PPB * CFEAT; idx += 256) {
            int p = idx / CFEAT, k = idx - p * CFEAT;
            sm.m.rows[p][k] = src[idx];
        }
        if (t < PPB) { sm.m.rows[t][22] = 0.f; sm.m.rows[t][23] = 0.f; }

        // per-thread weights: 2 channels, 24 padded k each
        const int c2 = (t & 127) * 2;  // channels c2, c2+1
        const int ps = t >> 7;         // pair slot parity 0/1
        float wA[24], wB[24];
        const float* wp = Wm1 + (long)c2 * CFEAT;
        #pragma unroll
        for (int k = 0; k < CFEAT; ++k) { wA[k] = wp[k]; wB[k] = wp[CFEAT + k]; }
        wA[22] = wA[23] = wB[22] = wB[23] = 0.f;
        const float b0 = bm1[c2], b1 = bm1[c2 + 1];
        __syncthreads();

        for (int it = 0; it < PPB / 2; ++it) {
            const int p = it * 2 + ps;            // half-block-uniform slot
            const long pair = pbase + p;
            const int r = (int)(pair & (RR - 1)); // pair % 1024
            float a0 = 0.f, a1 = 0.f;
            #pragma unroll
            for (int k4 = 0; k4 < 6; ++k4) {
                f4 mv = *(const f4*)&sm.m.rows[p][k4 * 4];  // broadcast b128
                a0 += mv.x * wA[k4 * 4 + 0]; a1 += mv.x * wB[k4 * 4 + 0];
                a0 += mv.y * wA[k4 * 4 + 1]; a1 += mv.y * wB[k4 * 4 + 1];
                a0 += mv.z * wA[k4 * 4 + 2]; a1 += mv.z * wB[k4 * 4 + 2];
                a0 += mv.w * wA[k4 * 4 + 3]; a1 += mv.w * wB[k4 * 4 + 3];
            }
            const f2 t2 = *(const f2*)(tm2 + (long)r * CMSA + c2);
            f2 o;
            o.x = a0 + b0 + t2.x;
            o.y = a1 + b1 + t2.y;
            __builtin_nontemporal_store(o, (f2*)(out_m + pair * CMSA + c2));
        }
    }
}

// ---------------------------------------------------------------------------
extern "C" void kernel_launch(void* const* d_in, const int* in_sizes, int n_in,
                              void* d_out, int out_size, void* d_ws, size_t ws_size,
                              hipStream_t stream) {
    const float* tf   = (const float*)d_in[0];
    const int*   resi = (const int*)  d_in[1];
    const float* msa  = (const float*)d_in[2];
    const float* Wa   = (const float*)d_in[3];
    const float* ba   = (const float*)d_in[4];
    const float* Wb   = (const float*)d_in[5];
    const float* bb   = (const float*)d_in[6];
    const float* Wm1  = (const float*)d_in[7];
    const float* bm1  = (const float*)d_in[8];
    const float* Wm2  = (const float*)d_in[9];
    const float* bm2  = (const float*)d_in[10];
    const float* Wpos = (const float*)d_in[11];
    const float* bpos = (const float*)d_in[12];

    float* out_m = (float*)d_out;                        // 128*1024*256
    float* out_z = out_m + (long)NSEQ * RR * CMSA;       // 1024*1024*128

    // workspace layout (floats): a | bv | tm2 | pose  (~2.13 MB total)
    float* a    = (float*)d_ws;
    float* bvp  = a   + (long)RR * CPAIR;
    float* tm2  = bvp + (long)RR * CPAIR;
    float* pose = tm2 + (long)RR * CMSA;

    k_pre<<<128, 256, 0, stream>>>(tf, Wa, ba, Wb, bb, Wm2, bm2, Wpos, bpos,
                                   a, bvp, tm2, pose);
    k_fused<<<4096, 256, 0, stream>>>(resi, a, bvp, pose, out_z,
                                      msa, Wm1, bm1, tm2, out_m);
}